// Round 8
// baseline (378.660 us; speedup 1.0000x reference)
//
#include <hip/hip_runtime.h>

#define N_PTS 500000
#define FEAT 24
#define HID 168
#define OUT_C 35
#define MT 64           // points per block (2 waves x 32 points)
#define H_STR 168       // scratch row stride (ushorts): 336B, dword-stride 84
                        // == 20 (mod 32), gcd 4 -> b128 reads spread 8 banks,
                        // 2 lanes/bank = conflict-free (vs 176: 4-way)
#define WREG (32 * H_STR + 32)   // per-wave region + 32-ushort zeroed overhang pad

// ws layout (ushort elements), all weights in MFMA fragment-major order:
//   W1frag: [s][mt(12)][lane(64)][8]        at 0       (3*6144  = 18432)
//   W2frag: [s][kk(6)][mt(12)][lane][8]     at 18432   (3*36864 = 110592)
//   W3frag: [s][mt(3)][kk(6)][lane][8]      at 129024  (3*9216  = 27648)
#define WF1_OFF 0
#define WF2_OFF 18432
#define WF3_OFF 129024
#define W_TOTAL 156672
#define PL_S0 (W_TOTAL)                    // scale0: 3 * 128*128*8 = 393216
#define PL_S1 (PL_S0 + 393216)             // scale1: 3 * 256*256*8 = 1572864
#define PL_S2 (PL_S1 + 1572864)            // scale2: 3 * 512*512*8 = 6291456

typedef short bf16x8 __attribute__((ext_vector_type(8)));
typedef float f32x4 __attribute__((ext_vector_type(4)));

__device__ __forceinline__ unsigned short f2bf(float f) {
    union { float f; unsigned int u; } v; v.f = f;
    unsigned int u = v.u;
    return (unsigned short)((u + 0x7FFFu + ((u >> 16) & 1u)) >> 16);
}
__device__ __forceinline__ float bf2f(unsigned short h) {
    union { unsigned int u; float f; } v; v.u = ((unsigned int)h) << 16;
    return v.f;
}
// single-instruction RNE pack
__device__ __forceinline__ unsigned int pk_bf16(float a, float b) {
    unsigned int r;
    asm("v_cvt_pk_bf16_f32 %0, %1, %2" : "=v"(r) : "v"(a), "v"(b));
    return r;
}
__device__ __forceinline__ f32x4 mfma16(bf16x8 a, bf16x8 b, f32x4 c) {
    return __builtin_amdgcn_mfma_f32_16x16x32_bf16(a, b, c, 0, 0, 0);
}

__global__ __launch_bounds__(256) void prep_weights(
    const float* __restrict__ w1a, const float* __restrict__ w2a, const float* __restrict__ w3a,
    const float* __restrict__ w1b, const float* __restrict__ w2b, const float* __restrict__ w3b,
    const float* __restrict__ w1c, const float* __restrict__ w2c, const float* __restrict__ w3c,
    unsigned short* __restrict__ ws)
{
    int id = blockIdx.x * 256 + threadIdx.x;
    if (id >= W_TOTAL) return;
    const float* w1[3] = {w1a, w1b, w1c};
    const float* w2[3] = {w2a, w2b, w2c};
    const float* w3[3] = {w3a, w3b, w3c};
    float v = 0.f;
    if (id < WF2_OFF) {                       // W1frag [s][mt][lane][8]
        int s = id / 6144, r = id % 6144;
        int mt = r >> 9, q = r & 511, lane = q >> 3, j = q & 7;
        int n = mt * 16 + (lane & 15), k = (lane >> 4) * 8 + j;
        if (n < HID && k < FEAT) v = w1[s][k * HID + n];
    } else if (id < WF3_OFF) {                // W2frag [s][kk][mt][lane][8]
        int t = id - WF2_OFF;
        int s = t / 36864, r = t % 36864;
        int fi = r >> 9, q = r & 511, lane = q >> 3, j = q & 7;
        int kk = fi / 12, mt = fi % 12;
        int n = mt * 16 + (lane & 15), k = kk * 32 + (lane >> 4) * 8 + j;
        if (n < HID && k < HID) v = w2[s][k * HID + n];
    } else {                                  // W3frag [s][mt][kk][lane][8]
        int t = id - WF3_OFF;
        int s = t / 9216, r = t % 9216;
        int fi = r >> 9, q = r & 511, lane = q >> 3, j = q & 7;
        int mt = fi / 6, kk = fi % 6;
        int n = mt * 16 + (lane & 15), k = kk * 32 + (lane >> 4) * 8 + j;
        if (n < OUT_C && k < HID) v = w3[s][k * OUT_C + n];
    }
    ws[id] = f2bf(v);
}

// channel-last bf16 repack, coalesced both sides.
__global__ __launch_bounds__(256) void prep_planes(
    const float* __restrict__ xy0, const float* __restrict__ xz0, const float* __restrict__ yz0,
    const float* __restrict__ xy1, const float* __restrict__ xz1, const float* __restrict__ yz1,
    const float* __restrict__ xy2, const float* __restrict__ xz2, const float* __restrict__ yz2,
    unsigned short* __restrict__ ws)
{
    const float* pls[9] = {xy0, xz0, yz0, xy1, xz1, yz1, xy2, xz2, yz2};
    int b = blockIdx.x;
    int s, pl, chunk, SS, base;
    if (b < 192)        { s = 0; SS = 16384;  pl = b / 64;   chunk = b % 64;    base = PL_S0; }
    else if (b < 960)   { int t = b - 192; s = 1; SS = 65536;  pl = t / 256;  chunk = t % 256;  base = PL_S1; }
    else                { int t = b - 960; s = 2; SS = 262144; pl = t / 1024; chunk = t % 1024; base = PL_S2; }
    const float* src = pls[s * 3 + pl];
    int pos = chunk * 256 + threadIdx.x;
    uint4 pk;
    unsigned int* po = (unsigned int*)&pk;
    #pragma unroll
    for (int c = 0; c < 4; ++c) {
        float f0 = src[(2 * c)     * SS + pos];
        float f1 = src[(2 * c + 1) * SS + pos];
        po[c] = pk_bf16(f0, f1);
    }
    *reinterpret_cast<uint4*>(&ws[base + pl * SS * 8 + pos * 8]) = pk;
}

// Wave-autonomous (zero __syncthreads). Wave owns 32 points (2 n-tiles).
// R6 structure (8-reg GEMM2 accumulators, lazy GEMM3) + conflict-free H stride.
__global__ __launch_bounds__(128, 4) void tri_mlp(
    const float* __restrict__ xyz,
    const float* __restrict__ b1_0, const float* __restrict__ b2_0, const float* __restrict__ b3_0,
    const float* __restrict__ b1_1, const float* __restrict__ b2_1, const float* __restrict__ b3_1,
    const float* __restrict__ b1_2, const float* __restrict__ b2_2, const float* __restrict__ b3_2,
    const unsigned short* __restrict__ wpack,
    float* __restrict__ out)
{
    __shared__ __align__(16) unsigned short H[2 * WREG];   // 21632 B

    const int tid  = threadIdx.x;
    const int wave = tid >> 6;
    const int lane = tid & 63;
    const int quad = lane >> 4;
    const int l16  = lane & 15;
    const int p0   = blockIdx.x * MT;
    const int prow = wave * 32;              // this wave's first point row
    unsigned short* Hw = H + wave * WREG;    // wave-private region

    // zero the 32-ushort overhang pad (row 31's k-overhang reads, x zero weights).
    if (lane < 4) *reinterpret_cast<f32x4*>(&Hw[32 * H_STR + lane * 8]) = (f32x4){0.f, 0.f, 0.f, 0.f};

    // hoist xyz loads out of the scale loop
    float X[2], Y[2], Z[2];
    #pragma unroll
    for (int ni = 0; ni < 2; ++ni) {
        int gp = min(p0 + prow + ni * 16 + l16, N_PTS - 1);
        X[ni] = xyz[gp * 3 + 0];
        Y[ni] = xyz[gp * 3 + 1];
        Z[ni] = xyz[gp * 3 + 2];
    }

    // c3 pre-loaded with summed bias (accumulates across scales)
    f32x4 c3[2][3];
    #pragma unroll
    for (int mt = 0; mt < 3; ++mt) {
        f32x4 cb;
        #pragma unroll
        for (int r = 0; r < 4; ++r) {
            int ch = mt * 16 + quad * 4 + r;
            cb[r] = (ch < OUT_C) ? (b3_0[ch] + b3_1[ch] + b3_2[ch]) : 0.f;
        }
        c3[0][mt] = cb;
        c3[1][mt] = cb;
    }

    #pragma unroll 1
    for (int s = 0; s < 3; ++s) {
        const float *b1, *b2;
        int S, sbase;
        if (s == 0)      { b1 = b1_0; b2 = b2_0; S = 128; sbase = PL_S0; }
        else if (s == 1) { b1 = b1_1; b2 = b2_1; S = 256; sbase = PL_S1; }
        else             { b1 = b1_2; b2 = b2_2; S = 512; sbase = PL_S2; }

        // ---------- sampling -> B1 fragments (registers) ----------
        bf16x8 B1[2];
        #pragma unroll
        for (int ni = 0; ni < 2; ++ni) {
            uint4 pk = {0u, 0u, 0u, 0u};
            if (quad < 3) {
                float gx, gy;
                if (quad == 0)      { gx = Y[ni]; gy = X[ni]; }
                else if (quad == 1) { gx = Z[ni]; gy = X[ni]; }
                else                { gx = Z[ni]; gy = Y[ni]; }
                gx *= 0.5f; gy *= 0.5f;      // nrm = coord/2 for range [-2,2]
                float ix = (gx + 1.0f) * 0.5f * (float)(S - 1);
                float iy = (gy + 1.0f) * 0.5f * (float)(S - 1);
                float fx = floorf(ix), fy = floorf(iy);
                int x0 = (int)fx, y0 = (int)fy;
                float wx = ix - fx, wy = iy - fy;
                int x0c = min(max(x0, 0), S - 1);
                int x1c = min(x0 + 1, S - 1);
                int y0c = min(max(y0, 0), S - 1);
                int y1c = min(y0 + 1, S - 1);
                const unsigned short* pcl = wpack + sbase + (quad << 3) * S * S;
                uint4 q00 = *(const uint4*)&pcl[(y0c * S + x0c) * 8];
                uint4 q01 = *(const uint4*)&pcl[(y0c * S + x1c) * 8];
                uint4 q10 = *(const uint4*)&pcl[(y1c * S + x0c) * 8];
                uint4 q11 = *(const uint4*)&pcl[(y1c * S + x1c) * 8];
                float w00 = (1.f - wx) * (1.f - wy), w01 = wx * (1.f - wy);
                float w10 = (1.f - wx) * wy,         w11 = wx * wy;
                const unsigned int* u00 = (const unsigned int*)&q00;
                const unsigned int* u01 = (const unsigned int*)&q01;
                const unsigned int* u10 = (const unsigned int*)&q10;
                const unsigned int* u11 = (const unsigned int*)&q11;
                unsigned int* po = (unsigned int*)&pk;
                #pragma unroll
                for (int h = 0; h < 4; ++h) {
                    float a0 = bf2f((unsigned short)(u00[h] & 0xFFFF)) * w00
                             + bf2f((unsigned short)(u01[h] & 0xFFFF)) * w01
                             + bf2f((unsigned short)(u10[h] & 0xFFFF)) * w10
                             + bf2f((unsigned short)(u11[h] & 0xFFFF)) * w11;
                    float a1 = bf2f((unsigned short)(u00[h] >> 16)) * w00
                             + bf2f((unsigned short)(u01[h] >> 16)) * w01
                             + bf2f((unsigned short)(u10[h] >> 16)) * w10
                             + bf2f((unsigned short)(u11[h] >> 16)) * w11;
                    po[h] = pk_bf16(a0, a1);
                }
            }
            B1[ni] = *reinterpret_cast<bf16x8*>(&pk);
        }

        // ---------- GEMM1: h1^T = Wt1 @ feat^T -> wave-private H ----------
        // ch 168..175 (mt=10, quads 2,3) would clobber next row: skip.
        {
            const unsigned short* w1f = wpack + WF1_OFF + s * 6144;
            #pragma unroll
            for (int mt = 0; mt < 11; ++mt) {
                bf16x8 a = *(const bf16x8*)&w1f[mt * 512 + lane * 8];
                float4 bias = *(const float4*)&b1[min(mt * 16 + quad * 4, HID - 4)];
                f32x4 cb = {bias.x, bias.y, bias.z, bias.w};
                #pragma unroll
                for (int ni = 0; ni < 2; ++ni) {
                    f32x4 c = mfma16(a, B1[ni], cb);
                    unsigned int u0 = pk_bf16(fmaxf(c[0], 0.f), fmaxf(c[1], 0.f));
                    unsigned int u1 = pk_bf16(fmaxf(c[2], 0.f), fmaxf(c[3], 0.f));
                    if (mt < 10 || quad < 2)
                        *reinterpret_cast<uint2*>(&Hw[(ni * 16 + l16) * H_STR + mt * 16 + quad * 4]) =
                            make_uint2(u0, u1);
                }
            }
        }

        // ---------- read h1 back as B fragments (wave-private) ----------
        // MUST be fully preloaded: GEMM2 overwrites H in place.
        // kk=5 overhang (k>=168) reads next row's h / pad: finite x zero weights.
        bf16x8 B2[2][6];
        #pragma unroll
        for (int ni = 0; ni < 2; ++ni)
            #pragma unroll
            for (int kk = 0; kk < 6; ++kk)
                B2[ni][kk] = *(const bf16x8*)&Hw[(ni * 16 + l16) * H_STR + kk * 32 + quad * 8];

        // ---------- GEMM2: mt-loop, ONE live accumulator pair (8 regs) ----------
        {
            const unsigned short* w2f = wpack + WF2_OFF + s * 36864;
            #pragma unroll 1
            for (int mt = 0; mt < 11; ++mt) {
                float4 bias = *(const float4*)&b2[min(mt * 16 + quad * 4, HID - 4)];
                f32x4 c20 = {bias.x, bias.y, bias.z, bias.w};
                f32x4 c21 = c20;
                #pragma unroll
                for (int kk = 0; kk < 6; ++kk) {
                    bf16x8 a = *(const bf16x8*)&w2f[(kk * 12 + mt) * 512 + lane * 8];
                    c20 = mfma16(a, B2[0][kk], c20);
                    c21 = mfma16(a, B2[1][kk], c21);
                }
                if (mt < 10 || quad < 2) {
                    unsigned int u00 = pk_bf16(fmaxf(c20[0], 0.f), fmaxf(c20[1], 0.f));
                    unsigned int u01 = pk_bf16(fmaxf(c20[2], 0.f), fmaxf(c20[3], 0.f));
                    *reinterpret_cast<uint2*>(&Hw[(l16) * H_STR + mt * 16 + quad * 4]) =
                        make_uint2(u00, u01);
                    unsigned int u10 = pk_bf16(fmaxf(c21[0], 0.f), fmaxf(c21[1], 0.f));
                    unsigned int u11 = pk_bf16(fmaxf(c21[2], 0.f), fmaxf(c21[3], 0.f));
                    *reinterpret_cast<uint2*>(&Hw[(16 + l16) * H_STR + mt * 16 + quad * 4]) =
                        make_uint2(u10, u11);
                }
            }
        }

        // ---------- GEMM3: kk-outer, lazy B3 loads (8 regs; H is stable) ----------
        {
            const unsigned short* w3f = wpack + WF3_OFF + s * 9216;
            #pragma unroll 1
            for (int kk = 0; kk < 6; ++kk) {
                bf16x8 b30 = *(const bf16x8*)&Hw[(l16) * H_STR + kk * 32 + quad * 8];
                bf16x8 b31 = *(const bf16x8*)&Hw[(16 + l16) * H_STR + kk * 32 + quad * 8];
                #pragma unroll
                for (int mt = 0; mt < 3; ++mt) {
                    bf16x8 a = *(const bf16x8*)&w3f[(mt * 6 + kk) * 512 + lane * 8];
                    c3[0][mt] = mfma16(a, b30, c3[0][mt]);
                    c3[1][mt] = mfma16(a, b31, c3[1][mt]);
                }
            }
        }
    }

    // ---------- epilogue: activate -> stage f32 tile in LDS -> coalesced stores ----------
    float* Hf = (float*)Hw;                  // 32 rows x 35 f32 = 4480 B (region is 10816 B)
    #pragma unroll
    for (int ni = 0; ni < 2; ++ni) {
        int row = ni * 16 + l16;
        #pragma unroll
        for (int mt = 0; mt < 3; ++mt) {
            #pragma unroll
            for (int r = 0; r < 4; ++r) {
                int ch = mt * 16 + quad * 4 + r;
                if (ch < OUT_C) {
                    float v = c3[ni][mt][r];
                    if (ch >= 31 && ch < 34)      v = 1.0f / (1.0f + expf(-v));
                    else if (ch == 34)            v *= 10.0f;
                    Hf[row * 35 + ch] = v;
                }
            }
        }
    }
    // N_PTS % 32 == 0, so waves are either fully valid or fully out of range.
    if (p0 + prow < N_PTS) {
        const int base = (p0 + prow) * 35;   // dword index; (p0+prow)%32==0 -> 16B aligned
        #pragma unroll
        for (int t = 0; t < 5; ++t) {
            int off = t * 256 + lane * 4;    // 1120 dwords per wave
            if (off < 1120) {
                f32x4 v = *(const f32x4*)&Hf[off];
                __builtin_nontemporal_store(v, reinterpret_cast<f32x4*>(&out[base + off]));
            }
        }
    }
}

extern "C" void kernel_launch(void* const* d_in, const int* in_sizes, int n_in,
                              void* d_out, int out_size, void* d_ws, size_t ws_size,
                              hipStream_t stream) {
    (void)in_sizes; (void)n_in; (void)out_size; (void)ws_size;
    const float* xyz  = (const float*)d_in[0];
    const float* xy0  = (const float*)d_in[1];
    const float* xz0  = (const float*)d_in[2];
    const float* yz0  = (const float*)d_in[3];
    const float* w1_0 = (const float*)d_in[4];
    const float* b1_0 = (const float*)d_in[5];
    const float* w2_0 = (const float*)d_in[6];
    const float* b2_0 = (const float*)d_in[7];
    const float* w3_0 = (const float*)d_in[8];
    const float* b3_0 = (const float*)d_in[9];
    const float* xy1  = (const float*)d_in[10];
    const float* xz1  = (const float*)d_in[11];
    const float* yz1  = (const float*)d_in[12];
    const float* w1_1 = (const float*)d_in[13];
    const float* b1_1 = (const float*)d_in[14];
    const float* w2_1 = (const float*)d_in[15];
    const float* b2_1 = (const float*)d_in[16];
    const float* w3_1 = (const float*)d_in[17];
    const float* b3_1 = (const float*)d_in[18];
    const float* xy2  = (const float*)d_in[19];
    const float* xz2  = (const float*)d_in[20];
    const float* yz2  = (const float*)d_in[21];
    const float* w1_2 = (const float*)d_in[22];
    const float* b1_2 = (const float*)d_in[23];
    const float* w2_2 = (const float*)d_in[24];
    const float* b2_2 = (const float*)d_in[25];
    const float* w3_2 = (const float*)d_in[26];
    const float* b3_2 = (const float*)d_in[27];

    unsigned short* ws = (unsigned short*)d_ws;
    float* out = (float*)d_out;

    prep_weights<<<(W_TOTAL + 255) / 256, 256, 0, stream>>>(
        w1_0, w2_0, w3_0, w1_1, w2_1, w3_1, w1_2, w2_2, w3_2, ws);

    prep_planes<<<4032, 256, 0, stream>>>(
        xy0, xz0, yz0, xy1, xz1, yz1, xy2, xz2, yz2, ws);

    tri_mlp<<<(N_PTS + MT - 1) / MT, 128, 0, stream>>>(
        xyz,
        b1_0, b2_0, b3_0, b1_1, b2_1, b3_1, b1_2, b2_2, b3_2,
        ws, out);
}

// Round 9
// 351.613 us; speedup vs baseline: 1.0769x; 1.0769x over previous
//
#include <hip/hip_runtime.h>

#define N_PTS 500000
#define FEAT 24
#define HID 168
#define OUT_C 35
#define MT 64           // points per block (2 waves x 32 points)
#define H_STR 176       // scratch row stride (ushorts): 168 + 8-ushort hole
                        // hole[168..175] = {1.0, 0...} -> bias k-row input
#define WREG (32 * H_STR + 16)   // per-wave region incl 16-ushort overhang pad

// ws layout (ushort elements), all weights in MFMA fragment-major order:
//   W1frag: [s][mt(12)][lane(64)][8]        at 0       (3*6144  = 18432)
//     k=24 row carries b1 (bias-fold; B1 quad3 supplies 1.0)
//   W2frag: [s][kk(6)][mt(12)][lane][8]     at 18432   (3*36864 = 110592)
//     k=168 row carries b2 (H hole supplies 1.0)
//   W3frag: [s][mt(3)][kk(6)][lane][8]      at 129024  (3*9216  = 27648)
//     k=168 row carries b3
#define WF1_OFF 0
#define WF2_OFF 18432
#define WF3_OFF 129024
#define W_TOTAL 156672
#define PL_S0 (W_TOTAL)                    // scale0: 3 * 128*128*8 = 393216
#define PL_S1 (PL_S0 + 393216)             // scale1: 3 * 256*256*8 = 1572864
#define PL_S2 (PL_S1 + 1572864)            // scale2: 3 * 512*512*8 = 6291456

#define PREP_W_BLOCKS 612                  // 612*256 == W_TOTAL

typedef short bf16x8 __attribute__((ext_vector_type(8)));
typedef float f32x4 __attribute__((ext_vector_type(4)));

__device__ __forceinline__ unsigned short f2bf(float f) {
    union { float f; unsigned int u; } v; v.f = f;
    unsigned int u = v.u;
    return (unsigned short)((u + 0x7FFFu + ((u >> 16) & 1u)) >> 16);
}
__device__ __forceinline__ float bf2f(unsigned short h) {
    union { unsigned int u; float f; } v; v.u = ((unsigned int)h) << 16;
    return v.f;
}
// single-instruction RNE pack
__device__ __forceinline__ unsigned int pk_bf16(float a, float b) {
    unsigned int r;
    asm("v_cvt_pk_bf16_f32 %0, %1, %2" : "=v"(r) : "v"(a), "v"(b));
    return r;
}
__device__ __forceinline__ f32x4 mfma16(bf16x8 a, bf16x8 b, f32x4 c) {
    return __builtin_amdgcn_mfma_f32_16x16x32_bf16(a, b, c, 0, 0, 0);
}

// Merged prep: blocks [0, 612) pack weights (+bias k-rows), rest repack planes.
__global__ __launch_bounds__(256) void prep_all(
    const float* __restrict__ xy0, const float* __restrict__ xz0, const float* __restrict__ yz0,
    const float* __restrict__ xy1, const float* __restrict__ xz1, const float* __restrict__ yz1,
    const float* __restrict__ xy2, const float* __restrict__ xz2, const float* __restrict__ yz2,
    const float* __restrict__ w1a, const float* __restrict__ w2a, const float* __restrict__ w3a,
    const float* __restrict__ w1b, const float* __restrict__ w2b, const float* __restrict__ w3b,
    const float* __restrict__ w1c, const float* __restrict__ w2c, const float* __restrict__ w3c,
    const float* __restrict__ b1a, const float* __restrict__ b2a, const float* __restrict__ b3a,
    const float* __restrict__ b1b, const float* __restrict__ b2b, const float* __restrict__ b3b,
    const float* __restrict__ b1c, const float* __restrict__ b2c, const float* __restrict__ b3c,
    unsigned short* __restrict__ ws)
{
    if (blockIdx.x < PREP_W_BLOCKS) {
        int id = blockIdx.x * 256 + threadIdx.x;
        const float* w1[3] = {w1a, w1b, w1c};
        const float* w2[3] = {w2a, w2b, w2c};
        const float* w3[3] = {w3a, w3b, w3c};
        const float* b1[3] = {b1a, b1b, b1c};
        const float* b2[3] = {b2a, b2b, b2c};
        const float* b3[3] = {b3a, b3b, b3c};
        float v = 0.f;
        if (id < WF2_OFF) {                       // W1frag [s][mt][lane][8]
            int s = id / 6144, r = id % 6144;
            int mt = r >> 9, q = r & 511, lane = q >> 3, j = q & 7;
            int n = mt * 16 + (lane & 15), k = (lane >> 4) * 8 + j;
            if (n < HID) {
                if (k < FEAT)       v = w1[s][k * HID + n];
                else if (k == FEAT) v = b1[s][n];          // bias-fold k-row
            }
        } else if (id < WF3_OFF) {                // W2frag [s][kk][mt][lane][8]
            int t = id - WF2_OFF;
            int s = t / 36864, r = t % 36864;
            int fi = r >> 9, q = r & 511, lane = q >> 3, j = q & 7;
            int kk = fi / 12, mt = fi % 12;
            int n = mt * 16 + (lane & 15), k = kk * 32 + (lane >> 4) * 8 + j;
            if (n < HID) {
                if (k < HID)        v = w2[s][k * HID + n];
                else if (k == HID)  v = b2[s][n];          // bias-fold k-row
            }
        } else {                                  // W3frag [s][mt][kk][lane][8]
            int t = id - WF3_OFF;
            int s = t / 9216, r = t % 9216;
            int fi = r >> 9, q = r & 511, lane = q >> 3, j = q & 7;
            int mt = fi / 6, kk = fi % 6;
            int n = mt * 16 + (lane & 15), k = kk * 32 + (lane >> 4) * 8 + j;
            if (n < OUT_C) {
                if (k < HID)        v = w3[s][k * OUT_C + n];
                else if (k == HID)  v = b3[s][n];          // bias-fold k-row
            }
        }
        ws[id] = f2bf(v);
        return;
    }

    const float* pls[9] = {xy0, xz0, yz0, xy1, xz1, yz1, xy2, xz2, yz2};
    int b = blockIdx.x - PREP_W_BLOCKS;
    int s, pl, chunk, SS, base;
    if (b < 192)        { s = 0; SS = 16384;  pl = b / 64;   chunk = b % 64;    base = PL_S0; }
    else if (b < 960)   { int t = b - 192; s = 1; SS = 65536;  pl = t / 256;  chunk = t % 256;  base = PL_S1; }
    else                { int t = b - 960; s = 2; SS = 262144; pl = t / 1024; chunk = t % 1024; base = PL_S2; }
    const float* src = pls[s * 3 + pl];
    int pos = chunk * 256 + threadIdx.x;
    uint4 pk;
    unsigned int* po = (unsigned int*)&pk;
    #pragma unroll
    for (int c = 0; c < 4; ++c) {
        float f0 = src[(2 * c)     * SS + pos];
        float f1 = src[(2 * c + 1) * SS + pos];
        po[c] = pk_bf16(f0, f1);
    }
    *reinterpret_cast<uint4*>(&ws[base + pl * SS * 8 + pos * 8]) = pk;
}

// Wave-autonomous (zero __syncthreads). Wave owns 32 points (2 n-tiles).
// R6/R7 structure (8-reg GEMM2 accumulators, lazy GEMM3) + bias-fold:
// no bias loads anywhere in the hot loop.
__global__ __launch_bounds__(128, 4) void tri_mlp(
    const float* __restrict__ xyz,
    const unsigned short* __restrict__ wpack,
    float* __restrict__ out)
{
    __shared__ __align__(16) unsigned short H[2 * WREG];   // 22592 B

    const int tid  = threadIdx.x;
    const int wave = tid >> 6;
    const int lane = tid & 63;
    const int quad = lane >> 4;
    const int l16  = lane & 15;
    const int p0   = blockIdx.x * MT;
    const int prow = wave * 32;              // this wave's first point row
    unsigned short* Hw = H + wave * WREG;    // wave-private region

    // one-time H region init:
    //  - hole [168..176) of each row = {bf16(1.0), 0 x7}: the k=168 bias input.
    //    (GEMM1/GEMM2 stores are predicated off ch>=168, so it persists.)
    //  - 16-ushort tail pad zeroed (row 31 kk=5 quad3 overhang, x zero weights).
    if (lane < 32)
        *reinterpret_cast<uint4*>(&Hw[lane * H_STR + HID]) = make_uint4(0x3F80u, 0u, 0u, 0u);
    if (lane < 8) ((unsigned int*)(Hw + 32 * H_STR))[lane] = 0u;

    // hoist xyz loads out of the scale loop
    float X[2], Y[2], Z[2];
    #pragma unroll
    for (int ni = 0; ni < 2; ++ni) {
        int gp = min(p0 + prow + ni * 16 + l16, N_PTS - 1);
        X[ni] = xyz[gp * 3 + 0];
        Y[ni] = xyz[gp * 3 + 1];
        Z[ni] = xyz[gp * 3 + 2];
    }

    // c3 accumulates across scales; bias arrives via the k=168 weight rows.
    f32x4 c3[2][3];
    #pragma unroll
    for (int mt = 0; mt < 3; ++mt) {
        c3[0][mt] = (f32x4){0.f, 0.f, 0.f, 0.f};
        c3[1][mt] = (f32x4){0.f, 0.f, 0.f, 0.f};
    }

    #pragma unroll 1
    for (int s = 0; s < 3; ++s) {
        int S, sbase;
        if (s == 0)      { S = 128; sbase = PL_S0; }
        else if (s == 1) { S = 256; sbase = PL_S1; }
        else             { S = 512; sbase = PL_S2; }

        // ---------- sampling -> B1 fragments (registers) ----------
        // quad 3 supplies the constant-1 feature at k=24 (bias k-row input).
        bf16x8 B1[2];
        #pragma unroll
        for (int ni = 0; ni < 2; ++ni) {
            uint4 pk = {0x3F80u, 0u, 0u, 0u};    // k=24 (quad3, j=0) = bf16(1.0)
            if (quad < 3) {
                float gx, gy;
                if (quad == 0)      { gx = Y[ni]; gy = X[ni]; }
                else if (quad == 1) { gx = Z[ni]; gy = X[ni]; }
                else                { gx = Z[ni]; gy = Y[ni]; }
                gx *= 0.5f; gy *= 0.5f;      // nrm = coord/2 for range [-2,2]
                float ix = (gx + 1.0f) * 0.5f * (float)(S - 1);
                float iy = (gy + 1.0f) * 0.5f * (float)(S - 1);
                float fx = floorf(ix), fy = floorf(iy);
                int x0 = (int)fx, y0 = (int)fy;
                float wx = ix - fx, wy = iy - fy;
                int x0c = min(max(x0, 0), S - 1);
                int x1c = min(x0 + 1, S - 1);
                int y0c = min(max(y0, 0), S - 1);
                int y1c = min(y0 + 1, S - 1);
                const unsigned short* pcl = wpack + sbase + (quad << 3) * S * S;
                uint4 q00 = *(const uint4*)&pcl[(y0c * S + x0c) * 8];
                uint4 q01 = *(const uint4*)&pcl[(y0c * S + x1c) * 8];
                uint4 q10 = *(const uint4*)&pcl[(y1c * S + x0c) * 8];
                uint4 q11 = *(const uint4*)&pcl[(y1c * S + x1c) * 8];
                float w00 = (1.f - wx) * (1.f - wy), w01 = wx * (1.f - wy);
                float w10 = (1.f - wx) * wy,         w11 = wx * wy;
                const unsigned int* u00 = (const unsigned int*)&q00;
                const unsigned int* u01 = (const unsigned int*)&q01;
                const unsigned int* u10 = (const unsigned int*)&q10;
                const unsigned int* u11 = (const unsigned int*)&q11;
                unsigned int* po = (unsigned int*)&pk;
                #pragma unroll
                for (int h = 0; h < 4; ++h) {
                    float a0 = bf2f((unsigned short)(u00[h] & 0xFFFF)) * w00
                             + bf2f((unsigned short)(u01[h] & 0xFFFF)) * w01
                             + bf2f((unsigned short)(u10[h] & 0xFFFF)) * w10
                             + bf2f((unsigned short)(u11[h] & 0xFFFF)) * w11;
                    float a1 = bf2f((unsigned short)(u00[h] >> 16)) * w00
                             + bf2f((unsigned short)(u01[h] >> 16)) * w01
                             + bf2f((unsigned short)(u10[h] >> 16)) * w10
                             + bf2f((unsigned short)(u11[h] >> 16)) * w11;
                    po[h] = pk_bf16(a0, a1);
                }
            }
            B1[ni] = *reinterpret_cast<bf16x8*>(&pk);
        }

        // ---------- GEMM1: h1^T = Wt1 @ feat^T -> wave-private H ----------
        // ch 168..175 (mt=10, quads 2,3) must not clobber the bias hole: skip.
        {
            const unsigned short* w1f = wpack + WF1_OFF + s * 6144;
            #pragma unroll
            for (int mt = 0; mt < 11; ++mt) {
                bf16x8 a = *(const bf16x8*)&w1f[mt * 512 + lane * 8];
                #pragma unroll
                for (int ni = 0; ni < 2; ++ni) {
                    f32x4 c = mfma16(a, B1[ni], (f32x4){0.f, 0.f, 0.f, 0.f});
                    unsigned int u0 = pk_bf16(fmaxf(c[0], 0.f), fmaxf(c[1], 0.f));
                    unsigned int u1 = pk_bf16(fmaxf(c[2], 0.f), fmaxf(c[3], 0.f));
                    if (mt < 10 || quad < 2)
                        *reinterpret_cast<uint2*>(&Hw[(ni * 16 + l16) * H_STR + mt * 16 + quad * 4]) =
                            make_uint2(u0, u1);
                }
            }
        }

        // ---------- read h1 back as B fragments (wave-private) ----------
        // MUST be fully preloaded: GEMM2 overwrites H in place.
        // kk=5: quad1 reads the hole {1.0,0..} (k=168 bias row), quads 2,3
        // overhang into next row / zeroed pad: finite x zero weights.
        bf16x8 B2[2][6];
        #pragma unroll
        for (int ni = 0; ni < 2; ++ni)
            #pragma unroll
            for (int kk = 0; kk < 6; ++kk)
                B2[ni][kk] = *(const bf16x8*)&Hw[(ni * 16 + l16) * H_STR + kk * 32 + quad * 8];

        // ---------- GEMM2: mt-loop, ONE live accumulator pair (8 regs) ----------
        {
            const unsigned short* w2f = wpack + WF2_OFF + s * 36864;
            #pragma unroll 1
            for (int mt = 0; mt < 11; ++mt) {
                f32x4 c20 = {0.f, 0.f, 0.f, 0.f};
                f32x4 c21 = c20;
                #pragma unroll
                for (int kk = 0; kk < 6; ++kk) {
                    bf16x8 a = *(const bf16x8*)&w2f[(kk * 12 + mt) * 512 + lane * 8];
                    c20 = mfma16(a, B2[0][kk], c20);
                    c21 = mfma16(a, B2[1][kk], c21);
                }
                if (mt < 10 || quad < 2) {
                    unsigned int u00 = pk_bf16(fmaxf(c20[0], 0.f), fmaxf(c20[1], 0.f));
                    unsigned int u01 = pk_bf16(fmaxf(c20[2], 0.f), fmaxf(c20[3], 0.f));
                    *reinterpret_cast<uint2*>(&Hw[(l16) * H_STR + mt * 16 + quad * 4]) =
                        make_uint2(u00, u01);
                    unsigned int u10 = pk_bf16(fmaxf(c21[0], 0.f), fmaxf(c21[1], 0.f));
                    unsigned int u11 = pk_bf16(fmaxf(c21[2], 0.f), fmaxf(c21[3], 0.f));
                    *reinterpret_cast<uint2*>(&Hw[(16 + l16) * H_STR + mt * 16 + quad * 4]) =
                        make_uint2(u10, u11);
                }
            }
        }

        // ---------- GEMM3: kk-outer, lazy B3 loads (8 regs; H is stable) ----------
        // kk=5 quad1 hole read supplies k=168 = 1.0 -> b3 row adds bias.
        {
            const unsigned short* w3f = wpack + WF3_OFF + s * 9216;
            #pragma unroll 1
            for (int kk = 0; kk < 6; ++kk) {
                bf16x8 b30 = *(const bf16x8*)&Hw[(l16) * H_STR + kk * 32 + quad * 8];
                bf16x8 b31 = *(const bf16x8*)&Hw[(16 + l16) * H_STR + kk * 32 + quad * 8];
                #pragma unroll
                for (int mt = 0; mt < 3; ++mt) {
                    bf16x8 a = *(const bf16x8*)&w3f[(mt * 6 + kk) * 512 + lane * 8];
                    c3[0][mt] = mfma16(a, b30, c3[0][mt]);
                    c3[1][mt] = mfma16(a, b31, c3[1][mt]);
                }
            }
        }
    }

    // ---------- epilogue: activate -> stage f32 tile in LDS -> coalesced stores ----------
    float* Hf = (float*)Hw;                  // 32 rows x 35 f32 = 4480 B (region is 11296 B)
    #pragma unroll
    for (int ni = 0; ni < 2; ++ni) {
        int row = ni * 16 + l16;
        #pragma unroll
        for (int mt = 0; mt < 3; ++mt) {
            #pragma unroll
            for (int r = 0; r < 4; ++r) {
                int ch = mt * 16 + quad * 4 + r;
                if (ch < OUT_C) {
                    float v = c3[ni][mt][r];
                    if (ch >= 31 && ch < 34)      v = 1.0f / (1.0f + expf(-v));
                    else if (ch == 34)            v *= 10.0f;
                    Hf[row * 35 + ch] = v;
                }
            }
        }
    }
    // N_PTS % 32 == 0, so waves are either fully valid or fully out of range.
    if (p0 + prow < N_PTS) {
        const int base = (p0 + prow) * 35;   // dword index; (p0+prow)%32==0 -> 16B aligned
        #pragma unroll
        for (int t = 0; t < 5; ++t) {
            int off = t * 256 + lane * 4;    // 1120 dwords per wave
            if (off < 1120) {
                f32x4 v = *(const f32x4*)&Hf[off];
                __builtin_nontemporal_store(v, reinterpret_cast<f32x4*>(&out[base + off]));
            }
        }
    }
}

extern "C" void kernel_launch(void* const* d_in, const int* in_sizes, int n_in,
                              void* d_out, int out_size, void* d_ws, size_t ws_size,
                              hipStream_t stream) {
    (void)in_sizes; (void)n_in; (void)out_size; (void)ws_size;
    const float* xyz  = (const float*)d_in[0];
    const float* xy0  = (const float*)d_in[1];
    const float* xz0  = (const float*)d_in[2];
    const float* yz0  = (const float*)d_in[3];
    const float* w1_0 = (const float*)d_in[4];
    const float* b1_0 = (const float*)d_in[5];
    const float* w2_0 = (const float*)d_in[6];
    const float* b2_0 = (const float*)d_in[7];
    const float* w3_0 = (const float*)d_in[8];
    const float* b3_0 = (const float*)d_in[9];
    const float* xy1  = (const float*)d_in[10];
    const float* xz1  = (const float*)d_in[11];
    const float* yz1  = (const float*)d_in[12];
    const float* w1_1 = (const float*)d_in[13];
    const float* b1_1 = (const float*)d_in[14];
    const float* w2_1 = (const float*)d_in[15];
    const float* b2_1 = (const float*)d_in[16];
    const float* w3_1 = (const float*)d_in[17];
    const float* b3_1 = (const float*)d_in[18];
    const float* xy2  = (const float*)d_in[19];
    const float* xz2  = (const float*)d_in[20];
    const float* yz2  = (const float*)d_in[21];
    const float* w1_2 = (const float*)d_in[22];
    const float* b1_2 = (const float*)d_in[23];
    const float* w2_2 = (const float*)d_in[24];
    const float* b2_2 = (const float*)d_in[25];
    const float* w3_2 = (const float*)d_in[26];
    const float* b3_2 = (const float*)d_in[27];

    unsigned short* ws = (unsigned short*)d_ws;
    float* out = (float*)d_out;

    prep_all<<<PREP_W_BLOCKS + 4032, 256, 0, stream>>>(
        xy0, xz0, yz0, xy1, xz1, yz1, xy2, xz2, yz2,
        w1_0, w2_0, w3_0, w1_1, w2_1, w3_1, w1_2, w2_2, w3_2,
        b1_0, b2_0, b3_0, b1_1, b2_1, b3_1, b1_2, b2_2, b3_2,
        ws);

    tri_mlp<<<(N_PTS + MT - 1) / MT, 128, 0, stream>>>(xyz, ws, out);
}